// Round 2
// baseline (3243.777 us; speedup 1.0000x reference)
//
#include <hip/hip_runtime.h>
#include <math.h>

// TTT recurrence: one wave (64 lanes) per row, lane = hidden index.
// R5: W2 as packed f16 pairs, v_dot2_f32_f16 matvecs.
// R7: fast_tanh (exp2+rcp), DPP wave reduction for the head.
// R8: no hot-loop barriers (single wave, DS in-order).
// R11: merged BWD->FWD phases, incremental z1.
// R12: u = w3*(1-h2^2) broadcast (dl factored out), fused d-dots+w2c apply.
// R13 (this): LDS-FREE inner loop. The h1 and u all-lane broadcasts move
// from LDS (write->read round trip ~150 cyc exposed on the serial chain,
// twice per phase) to register gathers: per-lane f16 + DPP(row_shl:1)
// neighbor pack -> 32 x v_readlane -> 32 uniform packed-f16 pairs that
// feed v_dot2_f32_f16 / v_pk_fma_f16 directly. Costs ~+72 VALU/phase,
// removes ~230 cyc of LDS latency from the per-phase dependency chain.
// Also: 8-way split dot accumulators (chain 8->4 deep), wave_sum seeded
// with (b3-xt)/64 so it returns diff directly (pred only materialized on
// the final phase), dz1 = diff*rk2 collapses the post-reduction chain to
// one mul. hr[] is gone (hb[] uniforms serve both dots and applies).

#define TT  784
#define HH  64
#define LR  0.01f

typedef _Float16 h2v __attribute__((ext_vector_type(2)));
#define FDOT2(a, b, c) __builtin_amdgcn_fdot2((a), (b), (c), false)
#define BCI(i) __builtin_bit_cast(h2v, (i))
#define PKFMA(acc, a, b) acc = __builtin_elementwise_fma((a), (b), (acc))

// tanh(x) = 1 - 2/(exp2(2*log2e*x)+1); saturates exactly at +-1.
__device__ __forceinline__ float fast_tanh(float x) {
    float e = __builtin_amdgcn_exp2f(x * 2.885390081777926814f);
    float r = __builtin_amdgcn_rcpf(e + 1.0f);
    return fmaf(-2.0f, r, 1.0f);
}

template <int CTRL, int RMASK, bool BC_>
__device__ __forceinline__ float dpp_add(float x) {
    int t = __builtin_amdgcn_update_dpp(0, __builtin_bit_cast(int, x),
                                        CTRL, RMASK, 0xf, BC_);
    return x + __builtin_bit_cast(float, t);
}

// Full wave64 sum -> uniform value (DPP reduce, total in lane 63).
__device__ __forceinline__ float wave_sum(float x) {
    x = dpp_add<0x111, 0xf, true>(x);   // row_shr:1
    x = dpp_add<0x112, 0xf, true>(x);   // row_shr:2
    x = dpp_add<0x114, 0xf, true>(x);   // row_shr:4
    x = dpp_add<0x118, 0xf, true>(x);   // row_shr:8
    x = dpp_add<0x142, 0xa, false>(x);  // row_bcast:15 -> rows 1,3
    x = dpp_add<0x143, 0xc, false>(x);  // row_bcast:31 -> rows 2,3
    return __builtin_bit_cast(float,
        __builtin_amdgcn_readlane(__builtin_bit_cast(int, x), 63));
}

// dst[i] = src[i+1] within each row of 16 (invalid lanes -> 0; only even
// lanes' results are consumed, and (2k,2k+1) never crosses a row edge).
__device__ __forceinline__ int lane_shl1(int v) {
    return __builtin_amdgcn_update_dpp(0, v, 0x101, 0xf, 0xf, false);
}

__global__ __launch_bounds__(64, 2)
void ttt_kernel(const float* __restrict__ ts,
                const float* __restrict__ xs,
                const int*   __restrict__ mask,
                const float* __restrict__ W1,
                const float* __restrict__ b1,
                const float* __restrict__ W2,
                const float* __restrict__ b2,
                const float* __restrict__ W3,
                const float* __restrict__ b3,
                float* __restrict__ out)
{
    __shared__ float s_ts[TT];
    __shared__ float s_xs[TT];
    __shared__ float s_out[TT];
    __shared__ int   s_mask[TT - 1];

    const int row  = blockIdx.x;
    const int lane = threadIdx.x;  // 0..63

    for (int i = lane; i < TT; i += HH) {
        s_ts[i] = ts[i];
        s_xs[i] = xs[row * TT + i];
    }
    for (int i = lane; i < TT - 1; i += HH) s_mask[i] = mask[row * (TT - 1) + i];

    // Per-lane theta (f32 except W2 storage).
    float w1a = W1[2 * lane + 0];
    float w1b = W1[2 * lane + 1];
    float b1v = b1[lane];
    float b2v = b2[lane];
    float w3v = W3[lane];
    float b3v = b3[0];

    h2v w2r[HH / 2];  // (W2[lane][2k], W2[lane][2k+1])
    h2v w2c[HH / 2];  // (W2[2k][lane], W2[2k+1][lane])
#pragma unroll
    for (int k = 0; k < HH / 2; ++k) {
        w2r[k] = h2v{(_Float16)W2[lane * HH + 2 * k], (_Float16)W2[lane * HH + 2 * k + 1]};
        w2c[k] = h2v{(_Float16)W2[(2 * k) * HH + lane], (_Float16)W2[(2 * k + 1) * HH + lane]};
    }
    __syncthreads();  // one-time (staging); outside hot loop

    float t_prev = s_ts[0];
    const float x0 = s_xs[0];
    float x_hat  = x0;
    float x_prev = x0;
    if (lane == 0) s_out[0] = x0;

    int hb[32];              // uniform packed (f16 h1[2k], f16 h1[2k+1])
    int ub[32];              // uniform packed (f16 u[2k],  f16 u[2k+1])
    float  h1f, h2f, predf;  // own-lane h1, h2; uniform pred
    float  ul;               // own-lane u (f32 master copy)
    float  z1f;              // current z1 (incremental inside gs loop)
    float  sdz1 = 0.f;       // per-step sum of dz1
    float  tc = 0.f, x_true = 0.f, tin = 0.f, nls = 0.f;

    // All-lane broadcast without LDS: RNE f16 of own value, DPP-pack with
    // lane+1's f16, then 32 readlanes -> uniform pairs (identical to the
    // old s_h1h/s_uh broadcast values).
    auto GATHER = [&](float x, int* dst) {
        const int lo = (int)__builtin_bit_cast(unsigned short, (_Float16)x);
        const int nb = lane_shl1(lo);
        const int pk = lo | (nb << 16);
#pragma unroll
        for (int k = 0; k < 32; ++k)
            dst[k] = __builtin_amdgcn_readlane(pk, 2 * k);
    };

    // Merged phase: BWD of the current pred (diff = pred - xt given), then
    // the next forward. Returns the NEXT diff (non-final; wave_sum seeded
    // with (b3-xt)/64) or the next pred (final phase; seeded with b3/64).
    auto MERGED = [&](float diff, float xt, bool final_) -> float {
        // ---- backward scalar head (all off the critical chain)
        const float k12 = -2.0f * fmaf(h1f, h1f, -1.0f);  // 2*(1-h1_old^2)
        const float ndl = diff * (-2.0f * LR);            // -LR*dl
        w3v = fmaf(ndl, h2f, w3v);       // OLD h2 (this backward's fwd)
        b3v += ndl;
        b2v = fmaf(ndl, ul, b2v);
        const _Float16 sd = (_Float16)(ndl * ul);     // -LR*dz2s (own lane)
        const h2v sdv = h2v{sd, sd};
        const _Float16 sh = (_Float16)(ndl * h1f);    // -LR*dl*h1_old
        const h2v shv = h2v{sh, sh};
        // ---- fused: d-dots on OLD w2c + w2c update, uniform ub (no LDS)
        float d0 = 0.f, d1 = 0.f, d2 = 0.f, d3 = 0.f;
        float d4 = 0.f, d5 = 0.f, d6 = 0.f, d7 = 0.f;
#pragma unroll
        for (int k = 0; k < 8; ++k) {
            const h2v q0 = BCI(ub[4 * k + 0]), q1 = BCI(ub[4 * k + 1]);
            const h2v q2 = BCI(ub[4 * k + 2]), q3 = BCI(ub[4 * k + 3]);
            if (k & 1) {
                d4 = FDOT2(w2c[4 * k + 0], q0, d4);
                d5 = FDOT2(w2c[4 * k + 1], q1, d5);
                d6 = FDOT2(w2c[4 * k + 2], q2, d6);
                d7 = FDOT2(w2c[4 * k + 3], q3, d7);
            } else {
                d0 = FDOT2(w2c[4 * k + 0], q0, d0);
                d1 = FDOT2(w2c[4 * k + 1], q1, d1);
                d2 = FDOT2(w2c[4 * k + 2], q2, d2);
                d3 = FDOT2(w2c[4 * k + 3], q3, d3);
            }
            PKFMA(w2c[4 * k + 0], shv, q0);
            PKFMA(w2c[4 * k + 1], shv, q1);
            PKFMA(w2c[4 * k + 2], shv, q2);
            PKFMA(w2c[4 * k + 3], shv, q3);
        }
        const float raw = ((d0 + d4) + (d1 + d5)) + ((d2 + d6) + (d3 + d7));
        const float rk2 = raw * k12;      // dz1 = diff * rk2
        const float dz1 = diff * rk2;
        sdz1 += dz1;
        // ---- next forward's z1 (+ materialization on the final phase)
        if (!final_) {
            z1f = fmaf(nls, dz1, z1f);   // exact: inputs fixed over gs loop
        } else {
            w1a = fmaf(-LR * tc,     sdz1, w1a);
            w1b = fmaf(-LR * x_prev, sdz1, w1b);
            b1v = fmaf(-LR,          sdz1, b1v);
            z1f = fmaf(w1a, tin, fmaf(w1b, x_true, b1v));
        }
        h1f = fast_tanh(z1f);
        // w2r apply with OLD hb (register-only), overlaps the new gather
#pragma unroll
        for (int k = 0; k < 32; ++k) PKFMA(w2r[k], sdv, BCI(hb[k]));
        GATHER(h1f, hb);                  // NEW h1 uniforms (no LDS)
        // ---- forward a-dots on updated w2r
        float a0 = b2v, a1 = 0.f, a2 = 0.f, a3 = 0.f;
        float a4 = 0.f, a5 = 0.f, a6 = 0.f, a7 = 0.f;
#pragma unroll
        for (int k = 0; k < 8; ++k) {
            const h2v q0 = BCI(hb[4 * k + 0]), q1 = BCI(hb[4 * k + 1]);
            const h2v q2 = BCI(hb[4 * k + 2]), q3 = BCI(hb[4 * k + 3]);
            if (k & 1) {
                a4 = FDOT2(w2r[4 * k + 0], q0, a4);
                a5 = FDOT2(w2r[4 * k + 1], q1, a5);
                a6 = FDOT2(w2r[4 * k + 2], q2, a6);
                a7 = FDOT2(w2r[4 * k + 3], q3, a7);
            } else {
                a0 = FDOT2(w2r[4 * k + 0], q0, a0);
                a1 = FDOT2(w2r[4 * k + 1], q1, a1);
                a2 = FDOT2(w2r[4 * k + 2], q2, a2);
                a3 = FDOT2(w2r[4 * k + 3], q3, a3);
            }
        }
        const float z2 = ((a0 + a4) + (a1 + a5)) + ((a2 + a6) + (a3 + a7));
        h2f = fast_tanh(z2);
        const float uf = w3v * fmaf(-h2f, h2f, 1.0f);
        ul = uf;
        GATHER(uf, ub);                   // next phase's d-dot uniforms
        // wave_sum returns diff (non-final) or pred (final) directly.
        const float cadd = (final_ ? b3v : (b3v - xt)) * 0.015625f;
        return wave_sum(fmaf(w3v, h2f, cadd));
    };

    // Pre-loop stash: theta0 forward at (ts[1], x0) = t=1's gs0 forward.
    z1f = fmaf(w1a, s_ts[1], fmaf(w1b, x0, b1v));
    h1f = fast_tanh(z1f);
    GATHER(h1f, hb);
    {
        float a0 = b2v, a1 = 0.f, a2 = 0.f, a3 = 0.f;
        float a4 = 0.f, a5 = 0.f, a6 = 0.f, a7 = 0.f;
#pragma unroll
        for (int k = 0; k < 8; ++k) {
            const h2v q0 = BCI(hb[4 * k + 0]), q1 = BCI(hb[4 * k + 1]);
            const h2v q2 = BCI(hb[4 * k + 2]), q3 = BCI(hb[4 * k + 3]);
            if (k & 1) {
                a4 = FDOT2(w2r[4 * k + 0], q0, a4);
                a5 = FDOT2(w2r[4 * k + 1], q1, a5);
                a6 = FDOT2(w2r[4 * k + 2], q2, a6);
                a7 = FDOT2(w2r[4 * k + 3], q3, a7);
            } else {
                a0 = FDOT2(w2r[4 * k + 0], q0, a0);
                a1 = FDOT2(w2r[4 * k + 1], q1, a1);
                a2 = FDOT2(w2r[4 * k + 2], q2, a2);
                a3 = FDOT2(w2r[4 * k + 3], q3, a3);
            }
        }
        const float z2 = ((a0 + a4) + (a1 + a5)) + ((a2 + a6) + (a3 + a7));
        h2f = fast_tanh(z2);
        const float uf = w3v * fmaf(-h2f, h2f, 1.0f);
        ul = uf;
        GATHER(uf, ub);
        predf = wave_sum(fmaf(w3v, h2f, b3v * 0.015625f));
    }

    for (int t = 1; t < TT; ++t) {
        tc     = s_ts[t];
        x_true = s_xs[t];
        tin    = tc + (tc - t_prev);
        nls    = -LR * fmaf(tc, tc, fmaf(x_prev, x_prev, 1.0f));
        const float x_t = s_mask[t - 1] ? x_true : x_hat;   // teacher forcing

        sdz1 = 0.f;
        float df = predf - x_t;           // gs0 backward's diff
        df    = MERGED(df, x_t, false);   // BWD gs0 + FWD gs1
        df    = MERGED(df, x_t, false);   // BWD gs1 + FWD gs2
        df    = MERGED(df, x_t, false);   // BWD gs2 + FWD gs3
        predf = MERGED(df, x_t, true);    // BWD gs3 + final forward
        x_hat = predf;

        if (lane == 0) s_out[t] = x_hat;
        t_prev = tc;
        x_prev = x_true;
    }

    // Coalesced flush of the row's outputs (single wave: no barrier needed).
    for (int i = lane; i < TT; i += HH) out[row * TT + i] = s_out[i];
}

extern "C" void kernel_launch(void* const* d_in, const int* in_sizes, int n_in,
                              void* d_out, int out_size, void* d_ws, size_t ws_size,
                              hipStream_t stream) {
    const float* ts   = (const float*)d_in[0];
    const float* xs   = (const float*)d_in[1];
    const int*   mask = (const int*)d_in[2];
    const float* W1   = (const float*)d_in[3];
    const float* b1   = (const float*)d_in[4];
    const float* W2   = (const float*)d_in[5];
    const float* b2   = (const float*)d_in[6];
    const float* W3   = (const float*)d_in[7];
    const float* b3   = (const float*)d_in[8];
    float* out = (float*)d_out;

    const int B = in_sizes[1] / TT;  // 2048
    dim3 grid(B), block(HH);
    hipLaunchKernelGGL(ttt_kernel, grid, block, 0, stream,
                       ts, xs, mask, W1, b1, W2, b2, W3, b3, out);
}